// Round 7
// baseline (261.924 us; speedup 1.0000x reference)
//
#include <hip/hip_runtime.h>
#include <math.h>

// B=4, N=256, D=256, H=8, DK=32, DV=32, R=64
constexpr int B_ = 4, N_ = 256, D_ = 256, H_ = 8, DK_ = 32, DV_ = 32, R_ = 64;
constexpr float SCALE_ = 0.17677669529663687f;  // 1/sqrt(32)
constexpr float EPS_ = 1e-6f;
constexpr int LST = 65;  // link LDS stride: bias phase (lane=j) 65%32=1 -> 2-way free;
                         // S phase (lane=r) stride-1 -> free

// ---------------------------------------------------------------------------
// K1: Ek = relationE @ Wr, Ev = relationE @ Wvv   ([64,256] @ [256,256])
__global__ __launch_bounds__(256) void ekev_kernel(
        const float* __restrict__ relE, const float* __restrict__ Wr,
        const float* __restrict__ Wvv, float* __restrict__ Ek,
        float* __restrict__ Ev) {
    int r = blockIdx.x & 63;
    int which = blockIdx.x >> 6;
    const float* W = which ? Wvv : Wr;
    float* out = which ? Ev : Ek;
    __shared__ float row[256];
    int tid = threadIdx.x;
    row[tid] = relE[r * 256 + tid];
    __syncthreads();
    float acc = 0.f;
    for (int d = 0; d < 256; ++d) acc += row[d] * W[d * 256 + tid];
    out[r * 256 + tid] = acc;
}

// ---------------------------------------------------------------------------
// K2: Mcat[d, h*64+r] = sum_dk Wq[d, h*32+dk] * Ek[r, h*32+dk]
__global__ __launch_bounds__(256) void mcat_kernel(
        const float* __restrict__ Wq, const float* __restrict__ Ek,
        float* __restrict__ M) {
    int d = blockIdx.x;
    int t = threadIdx.x;
    __shared__ float wrow[256];
    wrow[t] = Wq[d * 256 + t];
    __syncthreads();
    for (int hr = t; hr < 512; hr += 256) {
        int h = hr >> 6, r = hr & 63;
        const float4* ek4 = (const float4*)(Ek + r * 256 + h * 32);
        const float4* w4 = (const float4*)(wrow + h * 32);
        float acc = 0.f;
#pragma unroll
        for (int k = 0; k < 8; ++k) {
            float4 e = ek4[k], w = w4[k];
            acc += e.x * w.x + e.y * w.y + e.z * w.z + e.w * w.w;
        }
        M[d * 512 + hr] = acc;
    }
}

// ---------------------------------------------------------------------------
// K3: fused projection GEMM: [1024 x 1280] = q[1024,256] @ cat(Wq,Wk,Wv,Mcat)
// 64x64 tile, 16x16 threads, 4x4 acc. grid = 20*16 = 320.
__global__ __launch_bounds__(256) void projT_kernel(
        const float* __restrict__ q, const float* __restrict__ Wq,
        const float* __restrict__ Wk, const float* __restrict__ Wv,
        const float* __restrict__ M, float* __restrict__ Xq,
        float* __restrict__ Xk, float* __restrict__ Xv,
        float* __restrict__ T) {
    int ct = blockIdx.x >> 4, rt = blockIdx.x & 15;
    int t = threadIdx.x;
    __shared__ float ash[32 * 65];
    __shared__ float bsh[32 * 64];
    const float* W;
    int ncols, cbase;
    if (ct < 4)       { W = Wq; cbase = ct * 64;        ncols = 256; }
    else if (ct < 8)  { W = Wk; cbase = (ct - 4) * 64;  ncols = 256; }
    else if (ct < 12) { W = Wv; cbase = (ct - 8) * 64;  ncols = 256; }
    else              { W = M;  cbase = (ct - 12) * 64; ncols = 512; }
    int ti = t >> 4, tj = t & 15;
    float acc[4][4] = {{0.f}};
    for (int kc = 0; kc < 8; ++kc) {
        __syncthreads();
#pragma unroll
        for (int kk = 0; kk < 2; ++kk) {
            int m = t + kk * 256;
            int i = m >> 3, kq = m & 7;
            float4 v = *(const float4*)(q + (size_t)(rt * 64 + i) * 256 + kc * 32 + kq * 4);
            ash[(kq * 4 + 0) * 65 + i] = v.x;
            ash[(kq * 4 + 1) * 65 + i] = v.y;
            ash[(kq * 4 + 2) * 65 + i] = v.z;
            ash[(kq * 4 + 3) * 65 + i] = v.w;
        }
#pragma unroll
        for (int kk = 0; kk < 2; ++kk) {
            int m = t + kk * 256;
            int k = m >> 4, j4 = m & 15;
            float4 v = *(const float4*)(W + (size_t)(kc * 32 + k) * ncols + cbase + j4 * 4);
            *(float4*)(bsh + k * 64 + j4 * 4) = v;
        }
        __syncthreads();
#pragma unroll 8
        for (int k = 0; k < 32; ++k) {
            float4 av = *(const float4*)(ash + k * 65 + ti * 4);
            float4 bv = *(const float4*)(bsh + k * 64 + tj * 4);
            acc[0][0] += av.x * bv.x; acc[0][1] += av.x * bv.y;
            acc[0][2] += av.x * bv.z; acc[0][3] += av.x * bv.w;
            acc[1][0] += av.y * bv.x; acc[1][1] += av.y * bv.y;
            acc[1][2] += av.y * bv.z; acc[1][3] += av.y * bv.w;
            acc[2][0] += av.z * bv.x; acc[2][1] += av.z * bv.y;
            acc[2][2] += av.z * bv.z; acc[2][3] += av.z * bv.w;
            acc[3][0] += av.w * bv.x; acc[3][1] += av.w * bv.y;
            acc[3][2] += av.w * bv.z; acc[3][3] += av.w * bv.w;
        }
    }
    if (ct < 12) {
        float* dst = (ct < 4) ? Xq : (ct < 8) ? Xk : Xv;
        int gcol = (ct & 3) * 64 + tj * 4;
        int h = gcol >> 5, dk = gcol & 31;
#pragma unroll
        for (int a = 0; a < 4; ++a) {
            int row = rt * 64 + ti * 4 + a;
            int bb = row >> 8, n = row & 255;
            *(float4*)(dst + ((size_t)(bb * 8 + h) * 256 + n) * 32 + dk) =
                make_float4(acc[a][0], acc[a][1], acc[a][2], acc[a][3]);
        }
    } else {
        int gcol = (ct - 12) * 64 + tj * 4;
#pragma unroll
        for (int a = 0; a < 4; ++a) {
            int row = rt * 64 + ti * 4 + a;
            *(float4*)(T + (size_t)row * 512 + gcol) =
                make_float4(acc[a][0], acc[a][1], acc[a][2], acc[a][3]);
        }
    }
}

// ---------------------------------------------------------------------------
// K4: qk[b,h,i,j] = Xq[b,h,i,:].Xk[b,h,j,:]  — batched tiled GEMM, K=32
// grid = 512, block = 256 (16x16), 4x4 outs
__global__ __launch_bounds__(256) void qk_kernel(
        const float* __restrict__ Xq, const float* __restrict__ Xk,
        float* __restrict__ qk) {
    int x = blockIdx.x;
    int jt = x & 3, it = (x >> 2) & 3, bh = x >> 4;
    int t = threadIdx.x;
    __shared__ float xqsh[32 * 64];
    __shared__ float xksh[32 * 64];
#pragma unroll
    for (int k = 0; k < 2; ++k) {
        int m = t + k * 256;
        int i = m >> 3, dq4 = m & 7;
        float4 v = *(const float4*)(Xq + ((size_t)(bh * 256 + it * 64 + i)) * 32 + dq4 * 4);
        xqsh[(dq4 * 4 + 0) * 64 + i] = v.x;
        xqsh[(dq4 * 4 + 1) * 64 + i] = v.y;
        xqsh[(dq4 * 4 + 2) * 64 + i] = v.z;
        xqsh[(dq4 * 4 + 3) * 64 + i] = v.w;
        float4 u = *(const float4*)(Xk + ((size_t)(bh * 256 + jt * 64 + i)) * 32 + dq4 * 4);
        xksh[(dq4 * 4 + 0) * 64 + i] = u.x;
        xksh[(dq4 * 4 + 1) * 64 + i] = u.y;
        xksh[(dq4 * 4 + 2) * 64 + i] = u.z;
        xksh[(dq4 * 4 + 3) * 64 + i] = u.w;
    }
    __syncthreads();
    int ti = t >> 4, tj = t & 15;
    float acc[4][4] = {{0.f}};
#pragma unroll 8
    for (int dk = 0; dk < 32; ++dk) {
        float4 av = *(const float4*)(xqsh + dk * 64 + ti * 4);
        float4 bv = *(const float4*)(xksh + dk * 64 + tj * 4);
        acc[0][0] += av.x * bv.x; acc[0][1] += av.x * bv.y;
        acc[0][2] += av.x * bv.z; acc[0][3] += av.x * bv.w;
        acc[1][0] += av.y * bv.x; acc[1][1] += av.y * bv.y;
        acc[1][2] += av.y * bv.z; acc[1][3] += av.y * bv.w;
        acc[2][0] += av.z * bv.x; acc[2][1] += av.z * bv.y;
        acc[2][2] += av.z * bv.z; acc[2][3] += av.z * bv.w;
        acc[3][0] += av.w * bv.x; acc[3][1] += av.w * bv.y;
        acc[3][2] += av.w * bv.z; acc[3][3] += av.w * bv.w;
    }
#pragma unroll
    for (int a = 0; a < 4; ++a) {
        int i = it * 64 + ti * 4 + a;
        *(float4*)(qk + ((size_t)(bh * 256 + i)) * 256 + jt * 64 + tj * 4) =
            make_float4(acc[a][0], acc[a][1], acc[a][2], acc[a][3]);
    }
}

// ---------------------------------------------------------------------------
// K5: fused bias + softmax + S + Z per (b,i). link staged to LDS ONCE.
// grid = B*N = 1024, block = 512 (8 waves). LDS ~85 KB -> 1 block/CU.
__global__ __launch_bounds__(512) void fusedattn_kernel(
        const float* __restrict__ link, const float* __restrict__ Tg,
        const float* __restrict__ qk, const int* __restrict__ mask,
        const float* __restrict__ Xv, const float* __restrict__ Ev,
        float* __restrict__ alpha, float* __restrict__ Zx) {
    int bi = blockIdx.x;
    int b = bi >> 8, i = bi & 255;
    int t = threadIdx.x;
    __shared__ float linksh[256 * LST];  // 66.6 KB
    __shared__ float ashm[2048];         // alpha [h][j]  8 KB
    __shared__ float part[2048];         // partials / z-combine 8 KB
    __shared__ float Tsh[512];           // T, later S     2 KB
    __shared__ float redsh[64];          // [0:32) max, [32:64) sum

    // stage link[b,i,:,:] coalesced -> LDS (the ONLY HBM read of link)
    {
        const float4* lp = (const float4*)(link + (size_t)bi * 16384);
#pragma unroll
        for (int k = 0; k < 8; ++k) {
            int m = t + k * 512;         // float4 index 0..4095
            float4 v = lp[m];
            int j = m >> 4, c = (m & 15) * 4;
            float* dst = linksh + j * LST + c;
            dst[0] = v.x; dst[1] = v.y; dst[2] = v.z; dst[3] = v.w;
        }
    }
    Tsh[t] = Tg[(size_t)bi * 512 + t];
    float qkv[8];
    int mk = 1;
    if (t < 256) {
#pragma unroll
        for (int h = 0; h < 8; ++h)
            qkv[h] = qk[((size_t)(b * 8 + h) * 256 + i) * 256 + t];
        mk = mask[(b * 256 + i) * 256 + t];
    }
    __syncthreads();

    // bias: thread (j = t&255, rg = t>>8) covers 32 r's
    float pacc[8] = {0.f, 0.f, 0.f, 0.f, 0.f, 0.f, 0.f, 0.f};
    {
        int j = t & 255, r0 = (t >> 8) * 32;
#pragma unroll 8
        for (int rr = 0; rr < 32; ++rr) {
            int r = r0 + rr;
            float lv = linksh[j * LST + r];
#pragma unroll
            for (int h = 0; h < 8; ++h) pacc[h] += lv * Tsh[h * 64 + r];
        }
    }
    if (t >= 256) {
        int j = t & 255;
#pragma unroll
        for (int h = 0; h < 8; ++h) part[h * 256 + j] = pacc[h];
    }
    __syncthreads();

    // scores + softmax (j lives on threads 0..255; all threads hit barriers)
    float s[8];
    int lane = t & 63, wv = t >> 6;
    if (t < 256) {
#pragma unroll
        for (int h = 0; h < 8; ++h) {
            float v = (pacc[h] + part[h * 256 + t] + qkv[h]) * SCALE_;
            s[h] = (mk == 0) ? -1e9f : v;
            float m = s[h];
            for (int off = 32; off > 0; off >>= 1) m = fmaxf(m, __shfl_xor(m, off));
            if (lane == 0) redsh[h * 4 + wv] = m;
        }
    }
    __syncthreads();
    if (t < 256) {
#pragma unroll
        for (int h = 0; h < 8; ++h) {
            float mx = fmaxf(fmaxf(redsh[h * 4 + 0], redsh[h * 4 + 1]),
                             fmaxf(redsh[h * 4 + 2], redsh[h * 4 + 3]));
            float e = __expf(s[h] - mx);
            s[h] = e;
            float v = e;
            for (int off = 32; off > 0; off >>= 1) v += __shfl_xor(v, off);
            if (lane == 0) redsh[32 + h * 4 + wv] = v;
        }
    }
    __syncthreads();
    if (t < 256) {
#pragma unroll
        for (int h = 0; h < 8; ++h) {
            float esum = redsh[32 + h * 4 + 0] + redsh[32 + h * 4 + 1] +
                         redsh[32 + h * 4 + 2] + redsh[32 + h * 4 + 3];
            float a = s[h] * (1.f / esum);
            ashm[h * 256 + t] = a;
            alpha[((size_t)(b * 8 + h) * 256 + i) * 256 + t] = a;
        }
    }
    __syncthreads();

    // S[h][r] = sum_j alpha[h][j] * linksh[j][r]; 8 j-groups, two-pass combine
    float pacc2[8] = {0.f, 0.f, 0.f, 0.f, 0.f, 0.f, 0.f, 0.f};
    int r = t & 63, g = t >> 6;
    {
        int j0 = g * 32;
#pragma unroll 8
        for (int jj = 0; jj < 32; ++jj) {
            int j = j0 + jj;
            float lv = linksh[j * LST + r];
#pragma unroll
            for (int h = 0; h < 8; ++h) pacc2[h] += ashm[h * 256 + j] * lv;
        }
    }
    if (g >= 4) {
#pragma unroll
        for (int h = 0; h < 8; ++h) part[(g - 4) * 512 + h * 64 + r] = pacc2[h];
    }
    __syncthreads();
    if (g < 4) {
#pragma unroll
        for (int h = 0; h < 8; ++h) part[g * 512 + h * 64 + r] += pacc2[h];
    }
    __syncthreads();
    Tsh[t] = part[t] + part[512 + t] + part[1024 + t] + part[1536 + t];  // = S
    __syncthreads();

    // Z[h][dv] = sum_j alpha*Xv + sum_r S*Ev  (j split across thread halves)
    {
        int h = (t >> 5) & 7, dv = t & 31;
        float z = 0.f;
        const float* xv = Xv + ((size_t)(b * 8 + h) * 256) * 32 + dv;
        if (t < 256) {
#pragma unroll 4
            for (int j = 0; j < 128; ++j) z += ashm[h * 256 + j] * xv[j * 32];
        } else {
#pragma unroll 4
            for (int j = 128; j < 256; ++j) z += ashm[h * 256 + j] * xv[j * 32];
            const float* ev = Ev + h * 32 + dv;
#pragma unroll 4
            for (int rr = 0; rr < 64; ++rr) z += Tsh[h * 64 + rr] * ev[rr * 256];
        }
        part[t] = z;
    }
    __syncthreads();
    if (t < 256) {
        int h = t >> 5, dv = t & 31;
        Zx[((size_t)(b * 8 + h) * 256 + i) * 32 + dv] = part[t] + part[256 + t];
    }
}

// ---------------------------------------------------------------------------
// K6: out = Z @ Wo + residual -> LayerNorm. grid = 256 (4 rows), block = 256
__global__ __launch_bounds__(256) void outz_kernel(
        const float* __restrict__ Zx, const float* __restrict__ Wo,
        const float* __restrict__ q, const float* __restrict__ gamma,
        const float* __restrict__ beta, float* __restrict__ out) {
    int blk = blockIdx.x;
    int t = threadIdx.x;
    __shared__ float zsh[4 * 256];
    __shared__ float redsh[32];
    for (int m = t; m < 1024; m += 256) {
        int rr = m >> 8, d = m & 255;
        int h = d >> 5, dv = d & 31;
        int bn = blk * 4 + rr;
        int b = bn >> 8, i = bn & 255;
        zsh[rr * 256 + d] = Zx[((size_t)(b * 8 + h) * 256 + i) * 32 + dv];
    }
    __syncthreads();
    float acc[4];
#pragma unroll
    for (int rr = 0; rr < 4; ++rr) acc[rr] = q[(blk * 4 + rr) * 256 + t];
    for (int d4 = 0; d4 < 64; ++d4) {
        float w0 = Wo[(d4 * 4 + 0) * 256 + t];
        float w1 = Wo[(d4 * 4 + 1) * 256 + t];
        float w2 = Wo[(d4 * 4 + 2) * 256 + t];
        float w3 = Wo[(d4 * 4 + 3) * 256 + t];
#pragma unroll
        for (int rr = 0; rr < 4; ++rr) {
            float4 zv = *(const float4*)(zsh + rr * 256 + d4 * 4);
            acc[rr] += zv.x * w0 + zv.y * w1 + zv.z * w2 + zv.w * w3;
        }
    }
    int lane = t & 63, wv = t >> 6;
#pragma unroll
    for (int rr = 0; rr < 4; ++rr) {
        float v = acc[rr], v2 = acc[rr] * acc[rr];
        for (int off = 32; off > 0; off >>= 1) {
            v += __shfl_xor(v, off);
            v2 += __shfl_xor(v2, off);
        }
        if (lane == 0) {
            redsh[rr * 8 + wv] = v;
            redsh[rr * 8 + 4 + wv] = v2;
        }
    }
    __syncthreads();
#pragma unroll
    for (int rr = 0; rr < 4; ++rr) {
        float sum = redsh[rr * 8 + 0] + redsh[rr * 8 + 1] + redsh[rr * 8 + 2] + redsh[rr * 8 + 3];
        float sum2 = redsh[rr * 8 + 4] + redsh[rr * 8 + 5] + redsh[rr * 8 + 6] + redsh[rr * 8 + 7];
        float mu = sum * (1.f / 256.f);
        float var = sum2 * (1.f / 256.f) - mu * mu;
        float dev = acc[rr] - mu;
        out[(blk * 4 + rr) * 256 + t] = dev * rsqrtf(var + EPS_) * gamma[t] + beta[t];
    }
}

// ---------------------------------------------------------------------------
extern "C" void kernel_launch(void* const* d_in, const int* in_sizes, int n_in,
                              void* d_out, int out_size, void* d_ws, size_t ws_size,
                              hipStream_t stream) {
    const float* q     = (const float*)d_in[0];
    const int*   mask  = (const int*)d_in[3];
    const float* link  = (const float*)d_in[4];
    const float* Wq    = (const float*)d_in[5];
    const float* Wk    = (const float*)d_in[6];
    const float* Wr    = (const float*)d_in[7];
    const float* Wv    = (const float*)d_in[8];
    const float* Wvv   = (const float*)d_in[9];
    const float* relE  = (const float*)d_in[10];
    const float* Wo    = (const float*)d_in[11];
    const float* gamma = (const float*)d_in[12];
    const float* beta  = (const float*)d_in[13];

    float* out   = (float*)d_out;
    float* alpha = out + B_ * N_ * D_;      // second output, [B,H,N,N]

    float* ws    = (float*)d_ws;
    float* Ek    = ws;                         // 16384
    float* Ev    = Ek + 16384;                 // 16384
    float* Mcat  = Ev + 16384;                 // 131072
    float* Xq    = Mcat + 131072;              // 262144
    float* Xk    = Xq + 262144;                // 262144
    float* Xv    = Xk + 262144;                // 262144
    float* T     = Xv + 262144;                // 524288
    float* qkbuf = T + 524288;                 // 2097152
    float* Zx    = qkbuf + 2097152;            // 262144  (total ~15.5 MB)

    ekev_kernel<<<128, 256, 0, stream>>>(relE, Wr, Wvv, Ek, Ev);
    mcat_kernel<<<256, 256, 0, stream>>>(Wq, Ek, Mcat);
    projT_kernel<<<320, 256, 0, stream>>>(q, Wq, Wk, Wv, Mcat, Xq, Xk, Xv, T);
    qk_kernel<<<512, 256, 0, stream>>>(Xq, Xk, qkbuf);
    fusedattn_kernel<<<1024, 512, 0, stream>>>(link, T, qkbuf, mask, Xv, Ev,
                                               alpha, Zx);
    outz_kernel<<<256, 256, 0, stream>>>(Zx, Wo, q, gamma, beta, out);
}

// Round 8
// 208.914 us; speedup vs baseline: 1.2537x; 1.2537x over previous
//
#include <hip/hip_runtime.h>
#include <math.h>

// B=4, N=256, D=256, H=8, DK=32, DV=32, R=64
constexpr int B_ = 4, N_ = 256, D_ = 256, H_ = 8, DK_ = 32, DV_ = 32, R_ = 64;
constexpr float SCALE_ = 0.17677669529663687f;  // 1/sqrt(32)
constexpr float EPS_ = 1e-6f;

// ---------------------------------------------------------------------------
// K1: Ek = relationE @ Wr, Ev = relationE @ Wvv   ([64,256] @ [256,256])
__global__ __launch_bounds__(256) void ekev_kernel(
        const float* __restrict__ relE, const float* __restrict__ Wr,
        const float* __restrict__ Wvv, float* __restrict__ Ek,
        float* __restrict__ Ev) {
    int r = blockIdx.x & 63;
    int which = blockIdx.x >> 6;
    const float* W = which ? Wvv : Wr;
    float* out = which ? Ev : Ek;
    __shared__ float row[256];
    int tid = threadIdx.x;
    row[tid] = relE[r * 256 + tid];
    __syncthreads();
    float acc = 0.f;
    for (int d = 0; d < 256; ++d) acc += row[d] * W[d * 256 + tid];
    out[r * 256 + tid] = acc;
}

// ---------------------------------------------------------------------------
// K2: Mcat[d, h*64+r] = sum_dk Wq[d, h*32+dk] * Ek[r, h*32+dk]
__global__ __launch_bounds__(256) void mcat_kernel(
        const float* __restrict__ Wq, const float* __restrict__ Ek,
        float* __restrict__ M) {
    int d = blockIdx.x;
    int t = threadIdx.x;
    __shared__ float wrow[256];
    wrow[t] = Wq[d * 256 + t];
    __syncthreads();
    for (int hr = t; hr < 512; hr += 256) {
        int h = hr >> 6, r = hr & 63;
        const float4* ek4 = (const float4*)(Ek + r * 256 + h * 32);
        const float4* w4 = (const float4*)(wrow + h * 32);
        float acc = 0.f;
#pragma unroll
        for (int k = 0; k < 8; ++k) {
            float4 e = ek4[k], w = w4[k];
            acc += e.x * w.x + e.y * w.y + e.z * w.z + e.w * w.w;
        }
        M[d * 512 + hr] = acc;
    }
}

// ---------------------------------------------------------------------------
// K3: fused projection GEMM: [1024 x 1280] = q[1024,256] @ cat(Wq,Wk,Wv,Mcat)
// 64x64 tile, 16x16 threads, 4x4 acc. grid = 20*16 = 320.
__global__ __launch_bounds__(256) void projT_kernel(
        const float* __restrict__ q, const float* __restrict__ Wq,
        const float* __restrict__ Wk, const float* __restrict__ Wv,
        const float* __restrict__ M, float* __restrict__ Xq,
        float* __restrict__ Xk, float* __restrict__ Xv,
        float* __restrict__ T) {
    int ct = blockIdx.x >> 4, rt = blockIdx.x & 15;
    int t = threadIdx.x;
    __shared__ float ash[32 * 65];
    __shared__ float bsh[32 * 64];
    const float* W;
    int ncols, cbase;
    if (ct < 4)       { W = Wq; cbase = ct * 64;        ncols = 256; }
    else if (ct < 8)  { W = Wk; cbase = (ct - 4) * 64;  ncols = 256; }
    else if (ct < 12) { W = Wv; cbase = (ct - 8) * 64;  ncols = 256; }
    else              { W = M;  cbase = (ct - 12) * 64; ncols = 512; }
    int ti = t >> 4, tj = t & 15;
    float acc[4][4] = {{0.f}};
    for (int kc = 0; kc < 8; ++kc) {
        __syncthreads();
#pragma unroll
        for (int kk = 0; kk < 2; ++kk) {
            int m = t + kk * 256;
            int i = m >> 3, kq = m & 7;
            float4 v = *(const float4*)(q + (size_t)(rt * 64 + i) * 256 + kc * 32 + kq * 4);
            ash[(kq * 4 + 0) * 65 + i] = v.x;
            ash[(kq * 4 + 1) * 65 + i] = v.y;
            ash[(kq * 4 + 2) * 65 + i] = v.z;
            ash[(kq * 4 + 3) * 65 + i] = v.w;
        }
#pragma unroll
        for (int kk = 0; kk < 2; ++kk) {
            int m = t + kk * 256;
            int k = m >> 4, j4 = m & 15;
            float4 v = *(const float4*)(W + (size_t)(kc * 32 + k) * ncols + cbase + j4 * 4);
            *(float4*)(bsh + k * 64 + j4 * 4) = v;
        }
        __syncthreads();
#pragma unroll 8
        for (int k = 0; k < 32; ++k) {
            float4 av = *(const float4*)(ash + k * 65 + ti * 4);
            float4 bv = *(const float4*)(bsh + k * 64 + tj * 4);
            acc[0][0] += av.x * bv.x; acc[0][1] += av.x * bv.y;
            acc[0][2] += av.x * bv.z; acc[0][3] += av.x * bv.w;
            acc[1][0] += av.y * bv.x; acc[1][1] += av.y * bv.y;
            acc[1][2] += av.y * bv.z; acc[1][3] += av.y * bv.w;
            acc[2][0] += av.z * bv.x; acc[2][1] += av.z * bv.y;
            acc[2][2] += av.z * bv.z; acc[2][3] += av.z * bv.w;
            acc[3][0] += av.w * bv.x; acc[3][1] += av.w * bv.y;
            acc[3][2] += av.w * bv.z; acc[3][3] += av.w * bv.w;
        }
    }
    if (ct < 12) {
        float* dst = (ct < 4) ? Xq : (ct < 8) ? Xk : Xv;
        int gcol = (ct & 3) * 64 + tj * 4;
        int h = gcol >> 5, dk = gcol & 31;
#pragma unroll
        for (int a = 0; a < 4; ++a) {
            int row = rt * 64 + ti * 4 + a;
            int bb = row >> 8, n = row & 255;
            *(float4*)(dst + ((size_t)(bb * 8 + h) * 256 + n) * 32 + dk) =
                make_float4(acc[a][0], acc[a][1], acc[a][2], acc[a][3]);
        }
    } else {
        int gcol = (ct - 12) * 64 + tj * 4;
#pragma unroll
        for (int a = 0; a < 4; ++a) {
            int row = rt * 64 + ti * 4 + a;
            *(float4*)(T + (size_t)row * 512 + gcol) =
                make_float4(acc[a][0], acc[a][1], acc[a][2], acc[a][3]);
        }
    }
}

// ---------------------------------------------------------------------------
// K4: qk[b,h,i,j] = Xq[b,h,i,:].Xk[b,h,j,:]  — batched tiled GEMM, K=32
// grid = 512, block = 256 (16x16), 4x4 outs
__global__ __launch_bounds__(256) void qk_kernel(
        const float* __restrict__ Xq, const float* __restrict__ Xk,
        float* __restrict__ qk) {
    int x = blockIdx.x;
    int jt = x & 3, it = (x >> 2) & 3, bh = x >> 4;
    int t = threadIdx.x;
    __shared__ float xqsh[32 * 64];
    __shared__ float xksh[32 * 64];
#pragma unroll
    for (int k = 0; k < 2; ++k) {
        int m = t + k * 256;
        int i = m >> 3, dq4 = m & 7;
        float4 v = *(const float4*)(Xq + ((size_t)(bh * 256 + it * 64 + i)) * 32 + dq4 * 4);
        xqsh[(dq4 * 4 + 0) * 64 + i] = v.x;
        xqsh[(dq4 * 4 + 1) * 64 + i] = v.y;
        xqsh[(dq4 * 4 + 2) * 64 + i] = v.z;
        xqsh[(dq4 * 4 + 3) * 64 + i] = v.w;
        float4 u = *(const float4*)(Xk + ((size_t)(bh * 256 + jt * 64 + i)) * 32 + dq4 * 4);
        xksh[(dq4 * 4 + 0) * 64 + i] = u.x;
        xksh[(dq4 * 4 + 1) * 64 + i] = u.y;
        xksh[(dq4 * 4 + 2) * 64 + i] = u.z;
        xksh[(dq4 * 4 + 3) * 64 + i] = u.w;
    }
    __syncthreads();
    int ti = t >> 4, tj = t & 15;
    float acc[4][4] = {{0.f}};
#pragma unroll 8
    for (int dk = 0; dk < 32; ++dk) {
        float4 av = *(const float4*)(xqsh + dk * 64 + ti * 4);
        float4 bv = *(const float4*)(xksh + dk * 64 + tj * 4);
        acc[0][0] += av.x * bv.x; acc[0][1] += av.x * bv.y;
        acc[0][2] += av.x * bv.z; acc[0][3] += av.x * bv.w;
        acc[1][0] += av.y * bv.x; acc[1][1] += av.y * bv.y;
        acc[1][2] += av.y * bv.z; acc[1][3] += av.y * bv.w;
        acc[2][0] += av.z * bv.x; acc[2][1] += av.z * bv.y;
        acc[2][2] += av.z * bv.z; acc[2][3] += av.z * bv.w;
        acc[3][0] += av.w * bv.x; acc[3][1] += av.w * bv.y;
        acc[3][2] += av.w * bv.z; acc[3][3] += av.w * bv.w;
    }
#pragma unroll
    for (int a = 0; a < 4; ++a) {
        int i = it * 64 + ti * 4 + a;
        *(float4*)(qk + ((size_t)(bh * 256 + i)) * 256 + jt * 64 + tj * 4) =
            make_float4(acc[a][0], acc[a][1], acc[a][2], acc[a][3]);
    }
}

// ---------------------------------------------------------------------------
// K5: bias[b,h,i,j] = sum_r link[b,i,j,r] * T[bi][h*64+r]  (written to alpha slot)
// grid = 4096 (bi*4 + jt of 64 j), block = 256. The ONLY HBM pass over link.
__global__ __launch_bounds__(256) void bias_kernel(
        const float* __restrict__ link, const float* __restrict__ T,
        float* __restrict__ biasOut) {
    int x = blockIdx.x;
    int jt = x & 3, bi = x >> 2;
    int b = bi >> 8, i = bi & 255;
    int t = threadIdx.x;
    __shared__ float linksh[64 * 67];
    __shared__ float Tsh[512];
    __shared__ float part[4 * 512];
    Tsh[t] = T[(size_t)bi * 512 + t];
    Tsh[256 + t] = T[(size_t)bi * 512 + 256 + t];
    {
        const float4* lp = (const float4*)(link + ((size_t)(bi * 256 + jt * 64)) * 64);
#pragma unroll
        for (int k = 0; k < 4; ++k) {
            int m = t + k * 256;
            float4 v = lp[m];
            int j = m >> 4, c = (m & 15) * 4;
            float* dst = linksh + j * 67 + c;
            dst[0] = v.x; dst[1] = v.y; dst[2] = v.z; dst[3] = v.w;
        }
    }
    __syncthreads();
    int j = t & 63, rg = t >> 6;
    float pacc[8] = {0.f, 0.f, 0.f, 0.f, 0.f, 0.f, 0.f, 0.f};
    for (int rr = 0; rr < 16; ++rr) {
        int r = rg * 16 + rr;
        float lv = linksh[j * 67 + r];
#pragma unroll
        for (int h = 0; h < 8; ++h) pacc[h] += lv * Tsh[h * 64 + r];
    }
#pragma unroll
    for (int h = 0; h < 8; ++h) part[rg * 512 + h * 64 + j] = pacc[h];
    __syncthreads();
    int hp = t >> 6;
#pragma unroll
    for (int e = 0; e < 2; ++e) {
        int h = hp * 2 + e;
        float sum = part[h * 64 + j] + part[512 + h * 64 + j] +
                    part[1024 + h * 64 + j] + part[1536 + h * 64 + j];
        biasOut[((size_t)(b * 8 + h) * 256 + i) * 256 + jt * 64 + j] = sum;
    }
}

// ---------------------------------------------------------------------------
// K6: fused softmax + S per (b,i). grid = 1024, block = 256 (4 waves).
// Softmax over j -> alpha (LDS + global). Then S[h][r] = sum_j alpha*link
// with DIRECT coalesced link reads (lane = r, L3-hot; no LDS staging).
// LDS ~16.5 KB -> ~8 blocks/CU.
__global__ __launch_bounds__(256) void smsp_kernel(
        const float* __restrict__ qk, const int* __restrict__ mask,
        const float* __restrict__ link, float* __restrict__ alpha,
        float* __restrict__ S) {
    int bi = blockIdx.x;
    int b = bi >> 8, i = bi & 255;
    int t = threadIdx.x;
    __shared__ float ashm[2048];   // alpha [h][j] 8 KB
    __shared__ float part[2048];   // S partials [g][h][r] 8 KB
    __shared__ float redsh[64];

    // ---- softmax (thread = j) ----
    int j = t;
    float s[8];
#pragma unroll
    for (int h = 0; h < 8; ++h) {
        size_t off = ((size_t)(b * 8 + h) * 256 + i) * 256 + j;
        s[h] = (qk[off] + alpha[off]) * SCALE_;
    }
    if (mask[(b * 256 + i) * 256 + j] == 0) {
#pragma unroll
        for (int h = 0; h < 8; ++h) s[h] = -1e9f;
    }
    int lane = t & 63, wv = t >> 6;
#pragma unroll
    for (int h = 0; h < 8; ++h) {
        float v = s[h];
        for (int off = 32; off > 0; off >>= 1) v = fmaxf(v, __shfl_xor(v, off));
        if (lane == 0) redsh[h * 4 + wv] = v;
    }
    __syncthreads();
    float mx[8];
#pragma unroll
    for (int h = 0; h < 8; ++h)
        mx[h] = fmaxf(fmaxf(redsh[h * 4 + 0], redsh[h * 4 + 1]),
                      fmaxf(redsh[h * 4 + 2], redsh[h * 4 + 3]));
    __syncthreads();
#pragma unroll
    for (int h = 0; h < 8; ++h) {
        float e = __expf(s[h] - mx[h]);
        s[h] = e;
        float v = e;
        for (int off = 32; off > 0; off >>= 1) v += __shfl_xor(v, off);
        if (lane == 0) redsh[32 + h * 4 + wv] = v;
    }
    __syncthreads();
#pragma unroll
    for (int h = 0; h < 8; ++h) {
        float esum = redsh[32 + h * 4 + 0] + redsh[32 + h * 4 + 1] +
                     redsh[32 + h * 4 + 2] + redsh[32 + h * 4 + 3];
        float a = s[h] * (1.f / esum);
        ashm[h * 256 + j] = a;
        alpha[((size_t)(b * 8 + h) * 256 + i) * 256 + j] = a;
    }
    __syncthreads();

    // ---- S (wave g owns j in [64g, 64g+64), lane = r; coalesced 256B loads) ----
    int r = t & 63, g = t >> 6;
    float pacc[8] = {0.f, 0.f, 0.f, 0.f, 0.f, 0.f, 0.f, 0.f};
    const float* lp = link + ((size_t)(bi * 256 + g * 64)) * 64 + r;
#pragma unroll 4
    for (int j4 = 0; j4 < 16; ++j4) {
        float l0 = lp[(j4 * 4 + 0) * 64];
        float l1 = lp[(j4 * 4 + 1) * 64];
        float l2 = lp[(j4 * 4 + 2) * 64];
        float l3 = lp[(j4 * 4 + 3) * 64];
#pragma unroll
        for (int h = 0; h < 8; ++h) {
            float4 a = *(const float4*)(ashm + h * 256 + g * 64 + j4 * 4);
            pacc[h] += a.x * l0 + a.y * l1 + a.z * l2 + a.w * l3;
        }
    }
#pragma unroll
    for (int h = 0; h < 8; ++h) part[g * 512 + h * 64 + r] = pacc[h];
    __syncthreads();
    for (int hr = t; hr < 512; hr += 256) {
        S[(size_t)bi * 512 + hr] =
            part[hr] + part[512 + hr] + part[1024 + hr] + part[1536 + hr];
    }
}

// ---------------------------------------------------------------------------
// K7: Zx[b,h,i,dv] = sum_j alpha[b,h,i,j] * Xv[b,h,j,dv]
// grid = 32 bh * 8 itiles = 256, block = 256, 4 outs/thread
__global__ __launch_bounds__(256) void zx_kernel(
        const float* __restrict__ alpha, const float* __restrict__ Xv,
        float* __restrict__ Zx) {
    int x = blockIdx.x;
    int it = x & 7, bh = x >> 3;
    int t = threadIdx.x;
    __shared__ float ashm[32 * 64];
    __shared__ float xvsh[64 * 32];
    int dv = t & 31, ig = t >> 5;
    float acc[4] = {0.f, 0.f, 0.f, 0.f};
    for (int cc = 0; cc < 4; ++cc) {
        __syncthreads();
#pragma unroll
        for (int k = 0; k < 2; ++k) {
            int m = t + k * 256;
            int i = m >> 4, jq = m & 15;
            float4 v = *(const float4*)(alpha + ((size_t)(bh * 256 + it * 32 + i)) * 256 + cc * 64 + jq * 4);
            float* dst = ashm + i * 64 + jq * 4;
            dst[0] = v.x; dst[1] = v.y; dst[2] = v.z; dst[3] = v.w;
            ((float4*)xvsh)[m] = *(const float4*)(Xv + ((size_t)(bh * 256 + cc * 64)) * 32 + m * 4);
        }
        __syncthreads();
        for (int j = 0; j < 64; ++j) {
            float xv = xvsh[j * 32 + dv];
#pragma unroll
            for (int ii = 0; ii < 4; ++ii)
                acc[ii] += ashm[(ig * 4 + ii) * 64 + j] * xv;
        }
    }
#pragma unroll
    for (int ii = 0; ii < 4; ++ii)
        Zx[((size_t)(bh * 256 + it * 32 + ig * 4 + ii)) * 32 + dv] = acc[ii];
}

// ---------------------------------------------------------------------------
// K8: Z-finalize (S.Ev + Zx) -> @Wo + residual -> LayerNorm
// grid = 256 (4 rows each), block = 256 (col)
__global__ __launch_bounds__(256) void outz_kernel(
        const float* __restrict__ S, const float* __restrict__ Zx,
        const float* __restrict__ Ev, const float* __restrict__ Wo,
        const float* __restrict__ q, const float* __restrict__ gamma,
        const float* __restrict__ beta, float* __restrict__ out) {
    int blk = blockIdx.x;
    int t = threadIdx.x;
    __shared__ float Ssh[4 * 512];
    __shared__ float zsh[4 * 256];
    __shared__ float redsh[32];
    for (int m = t; m < 2048; m += 256) {
        int rr = m >> 9, hr = m & 511;
        Ssh[m] = S[(size_t)(blk * 4 + rr) * 512 + hr];
    }
    __syncthreads();
    int h = t >> 5, dv = t & 31;
    int row0 = blk * 4;
    int b = row0 >> 8;
    float z[4];
#pragma unroll
    for (int rr = 0; rr < 4; ++rr) {
        int i = (row0 + rr) & 255;
        z[rr] = Zx[((size_t)((b * 8 + h) * 256 + i)) * 32 + dv];
    }
    for (int r = 0; r < 64; ++r) {
        float ev = Ev[r * 256 + h * 32 + dv];
#pragma unroll
        for (int rr = 0; rr < 4; ++rr) z[rr] += Ssh[rr * 512 + h * 64 + r] * ev;
    }
#pragma unroll
    for (int rr = 0; rr < 4; ++rr) zsh[rr * 256 + t] = z[rr];
    __syncthreads();
    float acc[4];
#pragma unroll
    for (int rr = 0; rr < 4; ++rr) acc[rr] = q[(row0 + rr) * 256 + t];
    for (int d4 = 0; d4 < 64; ++d4) {
        float w0 = Wo[(d4 * 4 + 0) * 256 + t];
        float w1 = Wo[(d4 * 4 + 1) * 256 + t];
        float w2 = Wo[(d4 * 4 + 2) * 256 + t];
        float w3 = Wo[(d4 * 4 + 3) * 256 + t];
#pragma unroll
        for (int rr = 0; rr < 4; ++rr) {
            float4 zv = *(const float4*)(zsh + rr * 256 + d4 * 4);
            acc[rr] += zv.x * w0 + zv.y * w1 + zv.z * w2 + zv.w * w3;
        }
    }
    int lane = t & 63, wv = t >> 6;
#pragma unroll
    for (int rr = 0; rr < 4; ++rr) {
        float v = acc[rr], v2 = acc[rr] * acc[rr];
        for (int off = 32; off > 0; off >>= 1) {
            v += __shfl_xor(v, off);
            v2 += __shfl_xor(v2, off);
        }
        if (lane == 0) {
            redsh[rr * 8 + wv] = v;
            redsh[rr * 8 + 4 + wv] = v2;
        }
    }
    __syncthreads();
#pragma unroll
    for (int rr = 0; rr < 4; ++rr) {
        float sum = redsh[rr * 8 + 0] + redsh[rr * 8 + 1] + redsh[rr * 8 + 2] + redsh[rr * 8 + 3];
        float sum2 = redsh[rr * 8 + 4] + redsh[rr * 8 + 5] + redsh[rr * 8 + 6] + redsh[rr * 8 + 7];
        float mu = sum * (1.f / 256.f);
        float var = sum2 * (1.f / 256.f) - mu * mu;
        float dev = acc[rr] - mu;
        out[(row0 + rr) * 256 + t] = dev * rsqrtf(var + EPS_) * gamma[t] + beta[t];
    }
}

// ---------------------------------------------------------------------------
extern "C" void kernel_launch(void* const* d_in, const int* in_sizes, int n_in,
                              void* d_out, int out_size, void* d_ws, size_t ws_size,
                              hipStream_t stream) {
    const float* q     = (const float*)d_in[0];
    const int*   mask  = (const int*)d_in[3];
    const float* link  = (const float*)d_in[4];
    const float* Wq    = (const float*)d_in[5];
    const float* Wk    = (const float*)d_in[6];
    const float* Wr    = (const float*)d_in[7];
    const float* Wv    = (const float*)d_in[8];
    const float* Wvv   = (const float*)d_in[9];
    const float* relE  = (const float*)d_in[10];
    const float* Wo    = (const float*)d_in[11];
    const float* gamma = (const float*)d_in[12];
    const float* beta  = (const float*)d_in[13];

    float* out   = (float*)d_out;
    float* alpha = out + B_ * N_ * D_;      // [B,H,N,N]; holds bias then alpha

    float* ws    = (float*)d_ws;
    float* Ek    = ws;                         // 16384
    float* Ev    = Ek + 16384;                 // 16384
    float* Mcat  = Ev + 16384;                 // 131072
    float* Xq    = Mcat + 131072;              // 262144
    float* Xk    = Xq + 262144;                // 262144
    float* Xv    = Xk + 262144;                // 262144
    float* T     = Xv + 262144;                // 524288
    float* qkbuf = T + 524288;                 // 2097152
    float* S     = qkbuf + 2097152;            // 524288
    float* Zx    = S + 524288;                 // 262144  (total ~17.5 MB)

    ekev_kernel<<<128, 256, 0, stream>>>(relE, Wr, Wvv, Ek, Ev);
    mcat_kernel<<<256, 256, 0, stream>>>(Wq, Ek, Mcat);
    projT_kernel<<<320, 256, 0, stream>>>(q, Wq, Wk, Wv, Mcat, Xq, Xk, Xv, T);
    qk_kernel<<<512, 256, 0, stream>>>(Xq, Xk, qkbuf);
    bias_kernel<<<4096, 256, 0, stream>>>(link, T, alpha);
    smsp_kernel<<<1024, 256, 0, stream>>>(qkbuf, mask, link, alpha, S);
    zx_kernel<<<256, 256, 0, stream>>>(alpha, Xv, Zx);
    outz_kernel<<<256, 256, 0, stream>>>(S, Zx, Ev, Wo, q, gamma, beta, out);
}

// Round 9
// 208.013 us; speedup vs baseline: 1.2592x; 1.0043x over previous
//
#include <hip/hip_runtime.h>
#include <math.h>

// B=4, N=256, D=256, H=8, DK=32, DV=32, R=64
constexpr int B_ = 4, N_ = 256, D_ = 256, H_ = 8, DK_ = 32, DV_ = 32, R_ = 64;
constexpr float SCALE_ = 0.17677669529663687f;  // 1/sqrt(32)
constexpr float EPS_ = 1e-6f;

// ---------------------------------------------------------------------------
// K1: Ek = relationE @ Wr, Ev = relationE @ Wvv   ([64,256] @ [256,256])
__global__ __launch_bounds__(256) void ekev_kernel(
        const float* __restrict__ relE, const float* __restrict__ Wr,
        const float* __restrict__ Wvv, float* __restrict__ Ek,
        float* __restrict__ Ev) {
    int r = blockIdx.x & 63;
    int which = blockIdx.x >> 6;
    const float* W = which ? Wvv : Wr;
    float* out = which ? Ev : Ek;
    __shared__ float row[256];
    int tid = threadIdx.x;
    row[tid] = relE[r * 256 + tid];
    __syncthreads();
    float acc = 0.f;
    for (int d = 0; d < 256; ++d) acc += row[d] * W[d * 256 + tid];
    out[r * 256 + tid] = acc;
}

// ---------------------------------------------------------------------------
// K2: Mcat[d, h*64+r] = sum_dk Wq[d, h*32+dk] * Ek[r, h*32+dk]
__global__ __launch_bounds__(256) void mcat_kernel(
        const float* __restrict__ Wq, const float* __restrict__ Ek,
        float* __restrict__ M) {
    int d = blockIdx.x;
    int t = threadIdx.x;
    __shared__ float wrow[256];
    wrow[t] = Wq[d * 256 + t];
    __syncthreads();
    for (int hr = t; hr < 512; hr += 256) {
        int h = hr >> 6, r = hr & 63;
        const float4* ek4 = (const float4*)(Ek + r * 256 + h * 32);
        const float4* w4 = (const float4*)(wrow + h * 32);
        float acc = 0.f;
#pragma unroll
        for (int k = 0; k < 8; ++k) {
            float4 e = ek4[k], w = w4[k];
            acc += e.x * w.x + e.y * w.y + e.z * w.z + e.w * w.w;
        }
        M[d * 512 + hr] = acc;
    }
}

// ---------------------------------------------------------------------------
// K3: fused projection GEMM: [1024 x 1280] = q[1024,256] @ cat(Wq,Wk,Wv,Mcat)
// 64x64 tile, 16x16 threads, 4x4 acc. grid = 20*16 = 320.
__global__ __launch_bounds__(256) void projT_kernel(
        const float* __restrict__ q, const float* __restrict__ Wq,
        const float* __restrict__ Wk, const float* __restrict__ Wv,
        const float* __restrict__ M, float* __restrict__ Xq,
        float* __restrict__ Xk, float* __restrict__ Xv,
        float* __restrict__ T) {
    int ct = blockIdx.x >> 4, rt = blockIdx.x & 15;
    int t = threadIdx.x;
    __shared__ float ash[32 * 65];
    __shared__ float bsh[32 * 64];
    const float* W;
    int ncols, cbase;
    if (ct < 4)       { W = Wq; cbase = ct * 64;        ncols = 256; }
    else if (ct < 8)  { W = Wk; cbase = (ct - 4) * 64;  ncols = 256; }
    else if (ct < 12) { W = Wv; cbase = (ct - 8) * 64;  ncols = 256; }
    else              { W = M;  cbase = (ct - 12) * 64; ncols = 512; }
    int ti = t >> 4, tj = t & 15;
    float acc[4][4] = {{0.f}};
    for (int kc = 0; kc < 8; ++kc) {
        __syncthreads();
#pragma unroll
        for (int kk = 0; kk < 2; ++kk) {
            int m = t + kk * 256;
            int i = m >> 3, kq = m & 7;
            float4 v = *(const float4*)(q + (size_t)(rt * 64 + i) * 256 + kc * 32 + kq * 4);
            ash[(kq * 4 + 0) * 65 + i] = v.x;
            ash[(kq * 4 + 1) * 65 + i] = v.y;
            ash[(kq * 4 + 2) * 65 + i] = v.z;
            ash[(kq * 4 + 3) * 65 + i] = v.w;
        }
#pragma unroll
        for (int kk = 0; kk < 2; ++kk) {
            int m = t + kk * 256;
            int k = m >> 4, j4 = m & 15;
            float4 v = *(const float4*)(W + (size_t)(kc * 32 + k) * ncols + cbase + j4 * 4);
            *(float4*)(bsh + k * 64 + j4 * 4) = v;
        }
        __syncthreads();
#pragma unroll 8
        for (int k = 0; k < 32; ++k) {
            float4 av = *(const float4*)(ash + k * 65 + ti * 4);
            float4 bv = *(const float4*)(bsh + k * 64 + tj * 4);
            acc[0][0] += av.x * bv.x; acc[0][1] += av.x * bv.y;
            acc[0][2] += av.x * bv.z; acc[0][3] += av.x * bv.w;
            acc[1][0] += av.y * bv.x; acc[1][1] += av.y * bv.y;
            acc[1][2] += av.y * bv.z; acc[1][3] += av.y * bv.w;
            acc[2][0] += av.z * bv.x; acc[2][1] += av.z * bv.y;
            acc[2][2] += av.z * bv.z; acc[2][3] += av.z * bv.w;
            acc[3][0] += av.w * bv.x; acc[3][1] += av.w * bv.y;
            acc[3][2] += av.w * bv.z; acc[3][3] += av.w * bv.w;
        }
    }
    if (ct < 12) {
        float* dst = (ct < 4) ? Xq : (ct < 8) ? Xk : Xv;
        int gcol = (ct & 3) * 64 + tj * 4;
        int h = gcol >> 5, dk = gcol & 31;
#pragma unroll
        for (int a = 0; a < 4; ++a) {
            int row = rt * 64 + ti * 4 + a;
            int bb = row >> 8, n = row & 255;
            *(float4*)(dst + ((size_t)(bb * 8 + h) * 256 + n) * 32 + dk) =
                make_float4(acc[a][0], acc[a][1], acc[a][2], acc[a][3]);
        }
    } else {
        int gcol = (ct - 12) * 64 + tj * 4;
#pragma unroll
        for (int a = 0; a < 4; ++a) {
            int row = rt * 64 + ti * 4 + a;
            *(float4*)(T + (size_t)row * 512 + gcol) =
                make_float4(acc[a][0], acc[a][1], acc[a][2], acc[a][3]);
        }
    }
}

// ---------------------------------------------------------------------------
// K4: qk[b,h,i,j] = Xq[b,h,i,:].Xk[b,h,j,:]  — batched tiled GEMM, K=32
// grid = 512, block = 256 (16x16), 4x4 outs
__global__ __launch_bounds__(256) void qk_kernel(
        const float* __restrict__ Xq, const float* __restrict__ Xk,
        float* __restrict__ qk) {
    int x = blockIdx.x;
    int jt = x & 3, it = (x >> 2) & 3, bh = x >> 4;
    int t = threadIdx.x;
    __shared__ float xqsh[32 * 64];
    __shared__ float xksh[32 * 64];
#pragma unroll
    for (int k = 0; k < 2; ++k) {
        int m = t + k * 256;
        int i = m >> 3, dq4 = m & 7;
        float4 v = *(const float4*)(Xq + ((size_t)(bh * 256 + it * 64 + i)) * 32 + dq4 * 4);
        xqsh[(dq4 * 4 + 0) * 64 + i] = v.x;
        xqsh[(dq4 * 4 + 1) * 64 + i] = v.y;
        xqsh[(dq4 * 4 + 2) * 64 + i] = v.z;
        xqsh[(dq4 * 4 + 3) * 64 + i] = v.w;
        float4 u = *(const float4*)(Xk + ((size_t)(bh * 256 + jt * 64 + i)) * 32 + dq4 * 4);
        xksh[(dq4 * 4 + 0) * 64 + i] = u.x;
        xksh[(dq4 * 4 + 1) * 64 + i] = u.y;
        xksh[(dq4 * 4 + 2) * 64 + i] = u.z;
        xksh[(dq4 * 4 + 3) * 64 + i] = u.w;
    }
    __syncthreads();
    int ti = t >> 4, tj = t & 15;
    float acc[4][4] = {{0.f}};
#pragma unroll 8
    for (int dk = 0; dk < 32; ++dk) {
        float4 av = *(const float4*)(xqsh + dk * 64 + ti * 4);
        float4 bv = *(const float4*)(xksh + dk * 64 + tj * 4);
        acc[0][0] += av.x * bv.x; acc[0][1] += av.x * bv.y;
        acc[0][2] += av.x * bv.z; acc[0][3] += av.x * bv.w;
        acc[1][0] += av.y * bv.x; acc[1][1] += av.y * bv.y;
        acc[1][2] += av.y * bv.z; acc[1][3] += av.y * bv.w;
        acc[2][0] += av.z * bv.x; acc[2][1] += av.z * bv.y;
        acc[2][2] += av.z * bv.z; acc[2][3] += av.z * bv.w;
        acc[3][0] += av.w * bv.x; acc[3][1] += av.w * bv.y;
        acc[3][2] += av.w * bv.z; acc[3][3] += av.w * bv.w;
    }
#pragma unroll
    for (int a = 0; a < 4; ++a) {
        int i = it * 64 + ti * 4 + a;
        *(float4*)(qk + ((size_t)(bh * 256 + i)) * 256 + jt * 64 + tj * 4) =
            make_float4(acc[a][0], acc[a][1], acc[a][2], acc[a][3]);
    }
}

// ---------------------------------------------------------------------------
// K5: fused bias + softmax + S per (b,i). grid = 1024, block = 256 (4 waves).
// Bias via four 64-j link chunks staged to LDS (the only HBM link pass);
// bias accumulates in LDS (no global round-trip). Then softmax; then
// S[h][r] with direct coalesced L3-hot link reads. LDS ~35.5 KB -> 4 blk/CU.
__global__ __launch_bounds__(256) void biassm_kernel(
        const float* __restrict__ link, const float* __restrict__ Tg,
        const float* __restrict__ qk, const int* __restrict__ mask,
        float* __restrict__ alpha, float* __restrict__ S) {
    int bi = blockIdx.x;
    int b = bi >> 8, i = bi & 255;
    int t = threadIdx.x;
    __shared__ float linksh[64 * 67];  // 17.2 KB (chunk buffer)
    __shared__ float Tsh[512];         // 2 KB
    __shared__ float ashm[2048];       // bias -> alpha [h][j] 8 KB
    __shared__ float part[2048];       // partials 8 KB
    __shared__ float redsh[64];
    Tsh[t] = Tg[(size_t)bi * 512 + t];
    Tsh[256 + t] = Tg[(size_t)bi * 512 + 256 + t];

    // ---- bias in 4 chunks of 64 j ----
    for (int c = 0; c < 4; ++c) {
        __syncthreads();  // Tsh ready (c=0); linksh/part reusable (c>0)
        const float4* lp = (const float4*)(link + ((size_t)(bi * 256 + c * 64)) * 64);
#pragma unroll
        for (int k = 0; k < 4; ++k) {
            int m = t + k * 256;
            float4 v = lp[m];
            int j = m >> 4, col = (m & 15) * 4;
            float* dst = linksh + j * 67 + col;
            dst[0] = v.x; dst[1] = v.y; dst[2] = v.z; dst[3] = v.w;
        }
        __syncthreads();
        int j = t & 63, rg = t >> 6;
        float pacc[8] = {0.f, 0.f, 0.f, 0.f, 0.f, 0.f, 0.f, 0.f};
        for (int rr = 0; rr < 16; ++rr) {
            int r = rg * 16 + rr;
            float lv = linksh[j * 67 + r];
#pragma unroll
            for (int h = 0; h < 8; ++h) pacc[h] += lv * Tsh[h * 64 + r];
        }
#pragma unroll
        for (int h = 0; h < 8; ++h) part[rg * 512 + h * 64 + j] = pacc[h];
        __syncthreads();
        if ((t >> 6) == c) {
            int jj = t & 63;
#pragma unroll
            for (int h = 0; h < 8; ++h)
                ashm[h * 256 + t] = part[h * 64 + jj] + part[512 + h * 64 + jj] +
                                    part[1024 + h * 64 + jj] + part[1536 + h * 64 + jj];
        }
    }
    __syncthreads();

    // ---- softmax (thread = j) ----
    int j = t;
    float s[8];
#pragma unroll
    for (int h = 0; h < 8; ++h) {
        size_t off = ((size_t)(b * 8 + h) * 256 + i) * 256 + j;
        s[h] = (qk[off] + ashm[h * 256 + j]) * SCALE_;
    }
    if (mask[(b * 256 + i) * 256 + j] == 0) {
#pragma unroll
        for (int h = 0; h < 8; ++h) s[h] = -1e9f;
    }
    int lane = t & 63, wv = t >> 6;
#pragma unroll
    for (int h = 0; h < 8; ++h) {
        float v = s[h];
        for (int off = 32; off > 0; off >>= 1) v = fmaxf(v, __shfl_xor(v, off));
        if (lane == 0) redsh[h * 4 + wv] = v;
    }
    __syncthreads();
    float mx[8];
#pragma unroll
    for (int h = 0; h < 8; ++h)
        mx[h] = fmaxf(fmaxf(redsh[h * 4 + 0], redsh[h * 4 + 1]),
                      fmaxf(redsh[h * 4 + 2], redsh[h * 4 + 3]));
    __syncthreads();
#pragma unroll
    for (int h = 0; h < 8; ++h) {
        float e = __expf(s[h] - mx[h]);
        s[h] = e;
        float v = e;
        for (int off = 32; off > 0; off >>= 1) v += __shfl_xor(v, off);
        if (lane == 0) redsh[32 + h * 4 + wv] = v;
    }
    __syncthreads();
#pragma unroll
    for (int h = 0; h < 8; ++h) {
        float esum = redsh[32 + h * 4 + 0] + redsh[32 + h * 4 + 1] +
                     redsh[32 + h * 4 + 2] + redsh[32 + h * 4 + 3];
        float a = s[h] * (1.f / esum);
        ashm[h * 256 + j] = a;
        alpha[((size_t)(b * 8 + h) * 256 + i) * 256 + j] = a;
    }
    __syncthreads();

    // ---- S (wave g owns j in [64g, 64g+64), lane = r; coalesced, L3-hot) ----
    int r = t & 63, g = t >> 6;
    float pacc2[8] = {0.f, 0.f, 0.f, 0.f, 0.f, 0.f, 0.f, 0.f};
    const float* lp2 = link + ((size_t)(bi * 256 + g * 64)) * 64 + r;
#pragma unroll 4
    for (int j4 = 0; j4 < 16; ++j4) {
        float l0 = lp2[(j4 * 4 + 0) * 64];
        float l1 = lp2[(j4 * 4 + 1) * 64];
        float l2 = lp2[(j4 * 4 + 2) * 64];
        float l3 = lp2[(j4 * 4 + 3) * 64];
#pragma unroll
        for (int h = 0; h < 8; ++h) {
            float4 a = *(const float4*)(ashm + h * 256 + g * 64 + j4 * 4);
            pacc2[h] += a.x * l0 + a.y * l1 + a.z * l2 + a.w * l3;
        }
    }
#pragma unroll
    for (int h = 0; h < 8; ++h) part[g * 512 + h * 64 + r] = pacc2[h];
    __syncthreads();
    for (int hr = t; hr < 512; hr += 256) {
        S[(size_t)bi * 512 + hr] =
            part[hr] + part[512 + hr] + part[1024 + hr] + part[1536 + hr];
    }
}

// ---------------------------------------------------------------------------
// K6: fused Z + output: Z[h][dv] = alpha.Xv + S.Ev, then @Wo + residual -> LN.
// grid = 512 (2 rows each), block = 256. LDS ~22.5 KB -> plenty resident.
__global__ __launch_bounds__(256) void zout_kernel(
        const float* __restrict__ alpha, const float* __restrict__ Xv,
        const float* __restrict__ S, const float* __restrict__ Ev,
        const float* __restrict__ Wo, const float* __restrict__ q,
        const float* __restrict__ gamma, const float* __restrict__ beta,
        float* __restrict__ out) {
    int blk = blockIdx.x;
    int row0 = blk * 2;                 // rows row0, row0+1 (same b)
    int b = row0 >> 8;
    int t = threadIdx.x;
    __shared__ float Ssh[2 * 512];      // 4 KB
    __shared__ float ashm[2 * 2048];    // alpha [rr][h][j] 16 KB
    __shared__ float zsh[2 * 256];      // 2 KB
    __shared__ float redsh[16];
    for (int m = t; m < 1024; m += 256)
        Ssh[m] = S[(size_t)(row0 + (m >> 9)) * 512 + (m & 511)];
    for (int m = t; m < 4096; m += 256) {
        int rr = m >> 11, h = (m >> 8) & 7, j = m & 255;
        ashm[m] = alpha[((size_t)(b * 8 + h) * 256 + ((row0 + rr) & 255)) * 256 + j];
    }
    __syncthreads();
    // phase 1: Z for both rows
    {
        int h = t >> 5, dv = t & 31;
        float z0 = 0.f, z1 = 0.f;
        const float* xv = Xv + ((size_t)(b * 8 + h) * 256) * 32 + dv;
#pragma unroll 4
        for (int j = 0; j < 256; ++j) {
            float x = xv[j * 32];
            z0 += ashm[h * 256 + j] * x;
            z1 += ashm[2048 + h * 256 + j] * x;
        }
#pragma unroll 4
        for (int r = 0; r < 64; ++r) {
            float ev = Ev[r * 256 + h * 32 + dv];
            z0 += Ssh[h * 64 + r] * ev;
            z1 += Ssh[512 + h * 64 + r] * ev;
        }
        zsh[t] = z0;
        zsh[256 + t] = z1;
    }
    __syncthreads();
    // phase 2: @Wo + residual + LayerNorm (col = t)
    float a0 = q[(size_t)row0 * 256 + t];
    float a1 = q[(size_t)(row0 + 1) * 256 + t];
    for (int d4 = 0; d4 < 64; ++d4) {
        float w0 = Wo[(d4 * 4 + 0) * 256 + t];
        float w1 = Wo[(d4 * 4 + 1) * 256 + t];
        float w2 = Wo[(d4 * 4 + 2) * 256 + t];
        float w3 = Wo[(d4 * 4 + 3) * 256 + t];
        float4 z0v = *(const float4*)(zsh + d4 * 4);
        float4 z1v = *(const float4*)(zsh + 256 + d4 * 4);
        a0 += z0v.x * w0 + z0v.y * w1 + z0v.z * w2 + z0v.w * w3;
        a1 += z1v.x * w0 + z1v.y * w1 + z1v.z * w2 + z1v.w * w3;
    }
    int lane = t & 63, wv = t >> 6;
    float acc2[2] = {a0, a1};
#pragma unroll
    for (int rr = 0; rr < 2; ++rr) {
        float v = acc2[rr], v2 = acc2[rr] * acc2[rr];
        for (int off = 32; off > 0; off >>= 1) {
            v += __shfl_xor(v, off);
            v2 += __shfl_xor(v2, off);
        }
        if (lane == 0) {
            redsh[rr * 8 + wv] = v;
            redsh[rr * 8 + 4 + wv] = v2;
        }
    }
    __syncthreads();
#pragma unroll
    for (int rr = 0; rr < 2; ++rr) {
        float sum = redsh[rr * 8 + 0] + redsh[rr * 8 + 1] + redsh[rr * 8 + 2] + redsh[rr * 8 + 3];
        float sum2 = redsh[rr * 8 + 4] + redsh[rr * 8 + 5] + redsh[rr * 8 + 6] + redsh[rr * 8 + 7];
        float mu = sum * (1.f / 256.f);
        float var = sum2 * (1.f / 256.f) - mu * mu;
        float dev = acc2[rr] - mu;
        out[(size_t)(row0 + rr) * 256 + t] = dev * rsqrtf(var + EPS_) * gamma[t] + beta[t];
    }
}

// ---------------------------------------------------------------------------
extern "C" void kernel_launch(void* const* d_in, const int* in_sizes, int n_in,
                              void* d_out, int out_size, void* d_ws, size_t ws_size,
                              hipStream_t stream) {
    const float* q     = (const float*)d_in[0];
    const int*   mask  = (const int*)d_in[3];
    const float* link  = (const float*)d_in[4];
    const float* Wq    = (const float*)d_in[5];
    const float* Wk    = (const float*)d_in[6];
    const float* Wr    = (const float*)d_in[7];
    const float* Wv    = (const float*)d_in[8];
    const float* Wvv   = (const float*)d_in[9];
    const float* relE  = (const float*)d_in[10];
    const float* Wo    = (const float*)d_in[11];
    const float* gamma = (const float*)d_in[12];
    const float* beta  = (const float*)d_in[13];

    float* out   = (float*)d_out;
    float* alpha = out + B_ * N_ * D_;      // second output [B,H,N,N]

    float* ws    = (float*)d_ws;
    float* Ek    = ws;                         // 16384
    float* Ev    = Ek + 16384;                 // 16384
    float* Mcat  = Ev + 16384;                 // 131072
    float* Xq    = Mcat + 131072;              // 262144
    float* Xk    = Xq + 262144;                // 262144
    float* Xv    = Xk + 262144;                // 262144
    float* T     = Xv + 262144;                // 524288
    float* qkbuf = T + 524288;                 // 2097152
    float* S     = qkbuf + 2097152;            // 524288  (total ~15.5 MB)

    ekev_kernel<<<128, 256, 0, stream>>>(relE, Wr, Wvv, Ek, Ev);
    mcat_kernel<<<256, 256, 0, stream>>>(Wq, Ek, Mcat);
    projT_kernel<<<320, 256, 0, stream>>>(q, Wq, Wk, Wv, Mcat, Xq, Xk, Xv, T);
    qk_kernel<<<512, 256, 0, stream>>>(Xq, Xk, qkbuf);
    biassm_kernel<<<1024, 256, 0, stream>>>(link, T, qkbuf, mask, alpha, S);
    zout_kernel<<<512, 256, 0, stream>>>(alpha, Xv, S, Ev, Wo, q, gamma, beta, out);
}

// Round 10
// 205.871 us; speedup vs baseline: 1.2723x; 1.0104x over previous
//
#include <hip/hip_runtime.h>
#include <math.h>

// B=4, N=256, D=256, H=8, DK=32, DV=32, R=64
constexpr int B_ = 4, N_ = 256, D_ = 256, H_ = 8, DK_ = 32, DV_ = 32, R_ = 64;
constexpr float SCALE_ = 0.17677669529663687f;  // 1/sqrt(32)
constexpr float EPS_ = 1e-6f;

// ---------------------------------------------------------------------------
// K1: Ek = relationE @ Wr, Ev = relationE @ Wvv   ([64,256] @ [256,256])
__global__ __launch_bounds__(256) void ekev_kernel(
        const float* __restrict__ relE, const float* __restrict__ Wr,
        const float* __restrict__ Wvv, float* __restrict__ Ek,
        float* __restrict__ Ev) {
    int r = blockIdx.x & 63;
    int which = blockIdx.x >> 6;
    const float* W = which ? Wvv : Wr;
    float* out = which ? Ev : Ek;
    __shared__ float row[256];
    int tid = threadIdx.x;
    row[tid] = relE[r * 256 + tid];
    __syncthreads();
    float acc = 0.f;
    for (int d = 0; d < 256; ++d) acc += row[d] * W[d * 256 + tid];
    out[r * 256 + tid] = acc;
}

// ---------------------------------------------------------------------------
// K2: Mcat[d, h*64+r] = sum_dk Wq[d, h*32+dk] * Ek[r, h*32+dk]
__global__ __launch_bounds__(256) void mcat_kernel(
        const float* __restrict__ Wq, const float* __restrict__ Ek,
        float* __restrict__ M) {
    int d = blockIdx.x;
    int t = threadIdx.x;
    __shared__ float wrow[256];
    wrow[t] = Wq[d * 256 + t];
    __syncthreads();
    for (int hr = t; hr < 512; hr += 256) {
        int h = hr >> 6, r = hr & 63;
        const float4* ek4 = (const float4*)(Ek + r * 256 + h * 32);
        const float4* w4 = (const float4*)(wrow + h * 32);
        float acc = 0.f;
#pragma unroll
        for (int k = 0; k < 8; ++k) {
            float4 e = ek4[k], w = w4[k];
            acc += e.x * w.x + e.y * w.y + e.z * w.z + e.w * w.w;
        }
        M[d * 512 + hr] = acc;
    }
}

// ---------------------------------------------------------------------------
// K3: fused projection GEMM: [1024 x 1280] = q[1024,256] @ cat(Wq,Wk,Wv,Mcat)
// 64x64 tile, 16x16 threads, 4x4 acc. grid = 20*16 = 320.
__global__ __launch_bounds__(256) void projT_kernel(
        const float* __restrict__ q, const float* __restrict__ Wq,
        const float* __restrict__ Wk, const float* __restrict__ Wv,
        const float* __restrict__ M, float* __restrict__ Xq,
        float* __restrict__ Xk, float* __restrict__ Xv,
        float* __restrict__ T) {
    int ct = blockIdx.x >> 4, rt = blockIdx.x & 15;
    int t = threadIdx.x;
    __shared__ float ash[32 * 65];
    __shared__ float bsh[32 * 64];
    const float* W;
    int ncols, cbase;
    if (ct < 4)       { W = Wq; cbase = ct * 64;        ncols = 256; }
    else if (ct < 8)  { W = Wk; cbase = (ct - 4) * 64;  ncols = 256; }
    else if (ct < 12) { W = Wv; cbase = (ct - 8) * 64;  ncols = 256; }
    else              { W = M;  cbase = (ct - 12) * 64; ncols = 512; }
    int ti = t >> 4, tj = t & 15;
    float acc[4][4] = {{0.f}};
    for (int kc = 0; kc < 8; ++kc) {
        __syncthreads();
#pragma unroll
        for (int kk = 0; kk < 2; ++kk) {
            int m = t + kk * 256;
            int i = m >> 3, kq = m & 7;
            float4 v = *(const float4*)(q + (size_t)(rt * 64 + i) * 256 + kc * 32 + kq * 4);
            ash[(kq * 4 + 0) * 65 + i] = v.x;
            ash[(kq * 4 + 1) * 65 + i] = v.y;
            ash[(kq * 4 + 2) * 65 + i] = v.z;
            ash[(kq * 4 + 3) * 65 + i] = v.w;
        }
#pragma unroll
        for (int kk = 0; kk < 2; ++kk) {
            int m = t + kk * 256;
            int k = m >> 4, j4 = m & 15;
            float4 v = *(const float4*)(W + (size_t)(kc * 32 + k) * ncols + cbase + j4 * 4);
            *(float4*)(bsh + k * 64 + j4 * 4) = v;
        }
        __syncthreads();
#pragma unroll 8
        for (int k = 0; k < 32; ++k) {
            float4 av = *(const float4*)(ash + k * 65 + ti * 4);
            float4 bv = *(const float4*)(bsh + k * 64 + tj * 4);
            acc[0][0] += av.x * bv.x; acc[0][1] += av.x * bv.y;
            acc[0][2] += av.x * bv.z; acc[0][3] += av.x * bv.w;
            acc[1][0] += av.y * bv.x; acc[1][1] += av.y * bv.y;
            acc[1][2] += av.y * bv.z; acc[1][3] += av.y * bv.w;
            acc[2][0] += av.z * bv.x; acc[2][1] += av.z * bv.y;
            acc[2][2] += av.z * bv.z; acc[2][3] += av.z * bv.w;
            acc[3][0] += av.w * bv.x; acc[3][1] += av.w * bv.y;
            acc[3][2] += av.w * bv.z; acc[3][3] += av.w * bv.w;
        }
    }
    if (ct < 12) {
        float* dst = (ct < 4) ? Xq : (ct < 8) ? Xk : Xv;
        int gcol = (ct & 3) * 64 + tj * 4;
        int h = gcol >> 5, dk = gcol & 31;
#pragma unroll
        for (int a = 0; a < 4; ++a) {
            int row = rt * 64 + ti * 4 + a;
            int bb = row >> 8, n = row & 255;
            *(float4*)(dst + ((size_t)(bb * 8 + h) * 256 + n) * 32 + dk) =
                make_float4(acc[a][0], acc[a][1], acc[a][2], acc[a][3]);
        }
    } else {
        int gcol = (ct - 12) * 64 + tj * 4;
#pragma unroll
        for (int a = 0; a < 4; ++a) {
            int row = rt * 64 + ti * 4 + a;
            *(float4*)(T + (size_t)row * 512 + gcol) =
                make_float4(acc[a][0], acc[a][1], acc[a][2], acc[a][3]);
        }
    }
}

// ---------------------------------------------------------------------------
// K4: qk[b,h,i,j] = Xq[b,h,i,:].Xk[b,h,j,:]  — batched tiled GEMM, K=32
// grid = 512, block = 256 (16x16), 4x4 outs
__global__ __launch_bounds__(256) void qk_kernel(
        const float* __restrict__ Xq, const float* __restrict__ Xk,
        float* __restrict__ qk) {
    int x = blockIdx.x;
    int jt = x & 3, it = (x >> 2) & 3, bh = x >> 4;
    int t = threadIdx.x;
    __shared__ float xqsh[32 * 64];
    __shared__ float xksh[32 * 64];
#pragma unroll
    for (int k = 0; k < 2; ++k) {
        int m = t + k * 256;
        int i = m >> 3, dq4 = m & 7;
        float4 v = *(const float4*)(Xq + ((size_t)(bh * 256 + it * 64 + i)) * 32 + dq4 * 4);
        xqsh[(dq4 * 4 + 0) * 64 + i] = v.x;
        xqsh[(dq4 * 4 + 1) * 64 + i] = v.y;
        xqsh[(dq4 * 4 + 2) * 64 + i] = v.z;
        xqsh[(dq4 * 4 + 3) * 64 + i] = v.w;
        float4 u = *(const float4*)(Xk + ((size_t)(bh * 256 + jt * 64 + i)) * 32 + dq4 * 4);
        xksh[(dq4 * 4 + 0) * 64 + i] = u.x;
        xksh[(dq4 * 4 + 1) * 64 + i] = u.y;
        xksh[(dq4 * 4 + 2) * 64 + i] = u.z;
        xksh[(dq4 * 4 + 3) * 64 + i] = u.w;
    }
    __syncthreads();
    int ti = t >> 4, tj = t & 15;
    float acc[4][4] = {{0.f}};
#pragma unroll 8
    for (int dk = 0; dk < 32; ++dk) {
        float4 av = *(const float4*)(xqsh + dk * 64 + ti * 4);
        float4 bv = *(const float4*)(xksh + dk * 64 + tj * 4);
        acc[0][0] += av.x * bv.x; acc[0][1] += av.x * bv.y;
        acc[0][2] += av.x * bv.z; acc[0][3] += av.x * bv.w;
        acc[1][0] += av.y * bv.x; acc[1][1] += av.y * bv.y;
        acc[1][2] += av.y * bv.z; acc[1][3] += av.y * bv.w;
        acc[2][0] += av.z * bv.x; acc[2][1] += av.z * bv.y;
        acc[2][2] += av.z * bv.z; acc[2][3] += av.z * bv.w;
        acc[3][0] += av.w * bv.x; acc[3][1] += av.w * bv.y;
        acc[3][2] += av.w * bv.z; acc[3][3] += av.w * bv.w;
    }
#pragma unroll
    for (int a = 0; a < 4; ++a) {
        int i = it * 64 + ti * 4 + a;
        *(float4*)(qk + ((size_t)(bh * 256 + i)) * 256 + jt * 64 + tj * 4) =
            make_float4(acc[a][0], acc[a][1], acc[a][2], acc[a][3]);
    }
}

// ---------------------------------------------------------------------------
// K5: fused bias + softmax + S per (b,i). grid = 1024, block = 256 (4 waves).
// Link staged per 64-j chunk into an XOR-swizzled float4 layout so both the
// stage-write and the bias A-read are single ds_*_b128 ops (<=4-way aliasing).
// T dotted via float4 (4x fewer LDS issues than scalar). LDS ~34 KB -> 4 blk/CU.
__global__ __launch_bounds__(256) void biassm_kernel(
        const float* __restrict__ link, const float* __restrict__ Tg,
        const float* __restrict__ qk, const int* __restrict__ mask,
        float* __restrict__ alpha, float* __restrict__ S) {
    int bi = blockIdx.x;
    int b = bi >> 8, i = bi & 255;
    int t = threadIdx.x;
    __shared__ float4 linksh4[64 * 16];  // 16 KB, [j][rq ^ (j&15)]
    __shared__ float Tsh[512];           // 2 KB
    __shared__ float ashm[2048];         // bias -> alpha [h][j] 8 KB
    __shared__ float part[2048];         // partials 8 KB
    __shared__ float redsh[64];
    Tsh[t] = Tg[(size_t)bi * 512 + t];
    Tsh[256 + t] = Tg[(size_t)bi * 512 + 256 + t];

    // ---- bias in 4 chunks of 64 j ----
    for (int c = 0; c < 4; ++c) {
        __syncthreads();  // Tsh ready (c=0); linksh4/part reusable (c>0)
        {   // stage chunk: 4 float4 per thread, swizzled b128 writes
            const float4* lp = (const float4*)(link + ((size_t)(bi * 256 + c * 64)) * 64);
#pragma unroll
            for (int k = 0; k < 4; ++k) {
                int m = t + k * 256;          // float4 index 0..1023
                int j = m >> 4, rq = m & 15;
                linksh4[j * 16 + (rq ^ (j & 15))] = lp[m];
            }
        }
        __syncthreads();
        int j = t & 63, rg = t >> 6;
        float pacc[8] = {0.f, 0.f, 0.f, 0.f, 0.f, 0.f, 0.f, 0.f};
#pragma unroll
        for (int rq = 0; rq < 4; ++rq) {
            int r0 = rg * 16 + rq * 4;
            float4 lv = linksh4[j * 16 + ((rg * 4 + rq) ^ (j & 15))];
#pragma unroll
            for (int h = 0; h < 8; ++h) {
                float4 tv = *(const float4*)(Tsh + h * 64 + r0);
                pacc[h] += lv.x * tv.x + lv.y * tv.y + lv.z * tv.z + lv.w * tv.w;
            }
        }
#pragma unroll
        for (int h = 0; h < 8; ++h) part[rg * 512 + h * 64 + j] = pacc[h];
        __syncthreads();
        if ((t >> 6) == c) {
            int jj = t & 63;
#pragma unroll
            for (int h = 0; h < 8; ++h)
                ashm[h * 256 + t] = part[h * 64 + jj] + part[512 + h * 64 + jj] +
                                    part[1024 + h * 64 + jj] + part[1536 + h * 64 + jj];
        }
    }
    __syncthreads();

    // ---- softmax (thread = j) ----
    int j = t;
    float s[8];
#pragma unroll
    for (int h = 0; h < 8; ++h) {
        size_t off = ((size_t)(b * 8 + h) * 256 + i) * 256 + j;
        s[h] = (qk[off] + ashm[h * 256 + j]) * SCALE_;
    }
    if (mask[(b * 256 + i) * 256 + j] == 0) {
#pragma unroll
        for (int h = 0; h < 8; ++h) s[h] = -1e9f;
    }
    int lane = t & 63, wv = t >> 6;
#pragma unroll
    for (int h = 0; h < 8; ++h) {
        float v = s[h];
        for (int off = 32; off > 0; off >>= 1) v = fmaxf(v, __shfl_xor(v, off));
        if (lane == 0) redsh[h * 4 + wv] = v;
    }
    __syncthreads();
    float mx[8];
#pragma unroll
    for (int h = 0; h < 8; ++h)
        mx[h] = fmaxf(fmaxf(redsh[h * 4 + 0], redsh[h * 4 + 1]),
                      fmaxf(redsh[h * 4 + 2], redsh[h * 4 + 3]));
    __syncthreads();
#pragma unroll
    for (int h = 0; h < 8; ++h) {
        float e = __expf(s[h] - mx[h]);
        s[h] = e;
        float v = e;
        for (int off = 32; off > 0; off >>= 1) v += __shfl_xor(v, off);
        if (lane == 0) redsh[32 + h * 4 + wv] = v;
    }
    __syncthreads();
#pragma unroll
    for (int h = 0; h < 8; ++h) {
        float esum = redsh[32 + h * 4 + 0] + redsh[32 + h * 4 + 1] +
                     redsh[32 + h * 4 + 2] + redsh[32 + h * 4 + 3];
        float a = s[h] * (1.f / esum);
        ashm[h * 256 + j] = a;
        alpha[((size_t)(b * 8 + h) * 256 + i) * 256 + j] = a;
    }
    __syncthreads();

    // ---- S (wave g owns j in [64g, 64g+64), lane = r; coalesced, L3-hot) ----
    int r = t & 63, g = t >> 6;
    float pacc2[8] = {0.f, 0.f, 0.f, 0.f, 0.f, 0.f, 0.f, 0.f};
    const float* lp2 = link + ((size_t)(bi * 256 + g * 64)) * 64 + r;
#pragma unroll 4
    for (int j4 = 0; j4 < 16; ++j4) {
        float l0 = lp2[(j4 * 4 + 0) * 64];
        float l1 = lp2[(j4 * 4 + 1) * 64];
        float l2 = lp2[(j4 * 4 + 2) * 64];
        float l3 = lp2[(j4 * 4 + 3) * 64];
#pragma unroll
        for (int h = 0; h < 8; ++h) {
            float4 a = *(const float4*)(ashm + h * 256 + g * 64 + j4 * 4);
            pacc2[h] += a.x * l0 + a.y * l1 + a.z * l2 + a.w * l3;
        }
    }
#pragma unroll
    for (int h = 0; h < 8; ++h) part[g * 512 + h * 64 + r] = pacc2[h];
    __syncthreads();
    for (int hr = t; hr < 512; hr += 256) {
        S[(size_t)bi * 512 + hr] =
            part[hr] + part[512 + hr] + part[1024 + hr] + part[1536 + hr];
    }
}

// ---------------------------------------------------------------------------
// K6: fused Z + output: Z[h][dv] = alpha.Xv + S.Ev, then @Wo + residual -> LN.
// grid = 512 (2 rows each), block = 256.
__global__ __launch_bounds__(256) void zout_kernel(
        const float* __restrict__ alpha, const float* __restrict__ Xv,
        const float* __restrict__ S, const float* __restrict__ Ev,
        const float* __restrict__ Wo, const float* __restrict__ q,
        const float* __restrict__ gamma, const float* __restrict__ beta,
        float* __restrict__ out) {
    int blk = blockIdx.x;
    int row0 = blk * 2;                 // rows row0, row0+1 (same b)
    int b = row0 >> 8;
    int t = threadIdx.x;
    __shared__ float Ssh[2 * 512];      // 4 KB
    __shared__ float ashm[2 * 2048];    // alpha [rr][h][j] 16 KB
    __shared__ float zsh[2 * 256];      // 2 KB
    __shared__ float redsh[16];
    for (int m = t; m < 1024; m += 256)
        Ssh[m] = S[(size_t)(row0 + (m >> 9)) * 512 + (m & 511)];
    for (int m = t; m < 4096; m += 256) {
        int rr = m >> 11, h = (m >> 8) & 7, j = m & 255;
        ashm[m] = alpha[((size_t)(b * 8 + h) * 256 + ((row0 + rr) & 255)) * 256 + j];
    }
    __syncthreads();
    // phase 1: Z for both rows
    {
        int h = t >> 5, dv = t & 31;
        float z0 = 0.f, z1 = 0.f;
        const float* xv = Xv + ((size_t)(b * 8 + h) * 256) * 32 + dv;
#pragma unroll 4
        for (int j = 0; j < 256; ++j) {
            float x = xv[j * 32];
            z0 += ashm[h * 256 + j] * x;
            z1 += ashm[2048 + h * 256 + j] * x;
        }
#pragma unroll 4
        for (int r = 0; r < 64; ++r) {
            float ev = Ev[r * 256 + h * 32 + dv];
            z0 += Ssh[h * 64 + r] * ev;
            z1 += Ssh[512 + h * 64 + r] * ev;
        }
        zsh[t] = z0;
        zsh[256 + t] = z1;
    }
    __syncthreads();
    // phase 2: @Wo + residual + LayerNorm (col = t)
    float a0 = q[(size_t)row0 * 256 + t];
    float a1 = q[(size_t)(row0 + 1) * 256 + t];
    for (int d4 = 0; d4 < 64; ++d4) {
        float w0 = Wo[(d4 * 4 + 0) * 256 + t];
        float w1 = Wo[(d4 * 4 + 1) * 256 + t];
        float w2 = Wo[(d4 * 4 + 2) * 256 + t];
        float w3 = Wo[(d4 * 4 + 3) * 256 + t];
        float4 z0v = *(const float4*)(zsh + d4 * 4);
        float4 z1v = *(const float4*)(zsh + 256 + d4 * 4);
        a0 += z0v.x * w0 + z0v.y * w1 + z0v.z * w2 + z0v.w * w3;
        a1 += z1v.x * w0 + z1v.y * w1 + z1v.z * w2 + z1v.w * w3;
    }
    int lane = t & 63, wv = t >> 6;
    float acc2[2] = {a0, a1};
#pragma unroll
    for (int rr = 0; rr < 2; ++rr) {
        float v = acc2[rr], v2 = acc2[rr] * acc2[rr];
        for (int off = 32; off > 0; off >>= 1) {
            v += __shfl_xor(v, off);
            v2 += __shfl_xor(v2, off);
        }
        if (lane == 0) {
            redsh[rr * 8 + wv] = v;
            redsh[rr * 8 + 4 + wv] = v2;
        }
    }
    __syncthreads();
#pragma unroll
    for (int rr = 0; rr < 2; ++rr) {
        float sum = redsh[rr * 8 + 0] + redsh[rr * 8 + 1] + redsh[rr * 8 + 2] + redsh[rr * 8 + 3];
        float sum2 = redsh[rr * 8 + 4] + redsh[rr * 8 + 5] + redsh[rr * 8 + 6] + redsh[rr * 8 + 7];
        float mu = sum * (1.f / 256.f);
        float var = sum2 * (1.f / 256.f) - mu * mu;
        float dev = acc2[rr] - mu;
        out[(size_t)(row0 + rr) * 256 + t] = dev * rsqrtf(var + EPS_) * gamma[t] + beta[t];
    }
}

// ---------------------------------------------------------------------------
extern "C" void kernel_launch(void* const* d_in, const int* in_sizes, int n_in,
                              void* d_out, int out_size, void* d_ws, size_t ws_size,
                              hipStream_t stream) {
    const float* q     = (const float*)d_in[0];
    const int*   mask  = (const int*)d_in[3];
    const float* link  = (const float*)d_in[4];
    const float* Wq    = (const float*)d_in[5];
    const float* Wk    = (const float*)d_in[6];
    const float* Wr    = (const float*)d_in[7];
    const float* Wv    = (const float*)d_in[8];
    const float* Wvv   = (const float*)d_in[9];
    const float* relE  = (const float*)d_in[10];
    const float* Wo    = (const float*)d_in[11];
    const float* gamma = (const float*)d_in[12];
    const float* beta  = (const float*)d_in[13];

    float* out   = (float*)d_out;
    float* alpha = out + B_ * N_ * D_;      // second output [B,H,N,N]

    float* ws    = (float*)d_ws;
    float* Ek    = ws;                         // 16384
    float* Ev    = Ek + 16384;                 // 16384
    float* Mcat  = Ev + 16384;                 // 131072
    float* Xq    = Mcat + 131072;              // 262144
    float* Xk    = Xq + 262144;                // 262144
    float* Xv    = Xk + 262144;                // 262144
    float* T     = Xv + 262144;                // 524288
    float* qkbuf = T + 524288;                 // 2097152
    float* S     = qkbuf + 2097152;            // 524288  (total ~15.5 MB)

    ekev_kernel<<<128, 256, 0, stream>>>(relE, Wr, Wvv, Ek, Ev);
    mcat_kernel<<<256, 256, 0, stream>>>(Wq, Ek, Mcat);
    projT_kernel<<<320, 256, 0, stream>>>(q, Wq, Wk, Wv, Mcat, Xq, Xk, Xv, T);
    qk_kernel<<<512, 256, 0, stream>>>(Xq, Xk, qkbuf);
    biassm_kernel<<<1024, 256, 0, stream>>>(link, T, qkbuf, mask, alpha, S);
    zout_kernel<<<512, 256, 0, stream>>>(alpha, Xv, S, Ev, Wo, q, gamma, beta, out);
}